// Round 2
// baseline (105104.285 us; speedup 1.0000x reference)
//
#include <hip/hip_runtime.h>
#include <hip/hip_bf16.h>

#define T_STEPS 4096
#define HID 128
#define INP 8
#define ZXN 136   // HID + INP
#define MID 50
#define MIDP 52   // padded to multiple of 4
#define KSUB 10

__device__ __forceinline__ float fast_tanh(float x){
    // tanh(x) = 1 - 2/(exp(2x)+1); exp via v_exp_f32. Saturates correctly at +-inf.
    float e = __expf(2.0f * x);
    return 1.0f - 2.0f / (e + 1.0f);
}

__device__ __forceinline__ float softplus_f(float x){
    return (x > 20.0f) ? x : __logf(1.0f + __expf(x));
}

__global__ __launch_bounds__(64, 1)
void lode_kernel(const float* __restrict__ x, const float* __restrict__ dt,
                 const float* __restrict__ W1, const float* __restrict__ b1,
                 const float* __restrict__ W2, const float* __restrict__ b2,
                 const float* __restrict__ Wls1, const float* __restrict__ bls1,
                 const float* __restrict__ wls2, const float* __restrict__ bls2,
                 const float* __restrict__ Wlm1, const float* __restrict__ blm1,
                 float* __restrict__ out)
{
    __shared__ __align__(16) float zx[ZXN];   // [0..127]=z, [128..135]=x_t
    __shared__ __align__(16) float h1[64];    // mid activations (50 real, padded)

    const int l = threadIdx.x;

    // ---- per-lane weight registers (loaded once) ----
    // lane l owns W1 column l (output h1[l]); lanes 50..63 get zeros.
    float w1c[ZXN];
    #pragma unroll
    for (int k = 0; k < ZXN; ++k)
        w1c[k] = (l < MID) ? W1[k*MID + l] : 0.0f;
    const float b1c = (l < MID) ? b1[l] : 0.0f;

    // lane l owns W2 columns (2l, 2l+1); k padded to 52 with zeros.
    float2 w2p[MIDP];
    #pragma unroll
    for (int k = 0; k < MIDP; ++k){
        if (k < MID) w2p[k] = make_float2(W2[k*HID + 2*l], W2[k*HID + 2*l + 1]);
        else         w2p[k] = make_float2(0.0f, 0.0f);
    }
    const float2 b2p   = make_float2(b2[2*l],   b2[2*l+1]);
    const float2 bls1p = make_float2(bls1[2*l], bls1[2*l+1]);
    const float2 blm1p = make_float2(blm1[2*l], blm1[2*l+1]);
    const float2 wls2p = make_float2(wls2[2*l], wls2[2*l+1]);
    const float  bls2s = bls2[0];

    // z0 = 0
    float2 z2 = make_float2(0.0f, 0.0f);
    zx[2*l]   = 0.0f;
    zx[2*l+1] = 0.0f;
    __syncthreads();

    for (int t = 0; t < T_STEPS; ++t){
        if (l < INP) zx[HID + l] = x[t*INP + l];
        const float hstep = (dt[2*t+1] - dt[2*t]) * (1.0f / KSUB);
        __syncthreads();   // x-part visible; also orders prior heads-reads before z writes

        for (int s = 0; s < KSUB; ++s){
            // ---- phase A: h1[l] = tanh(b1[l] + sum_k zx[k]*W1[k][l]) ----
            float acc = b1c;
            #pragma unroll
            for (int m = 0; m < ZXN/4; ++m){
                const float4 zv = *reinterpret_cast<const float4*>(&zx[4*m]);
                acc = fmaf(zv.x, w1c[4*m+0], acc);
                acc = fmaf(zv.y, w1c[4*m+1], acc);
                acc = fmaf(zv.z, w1c[4*m+2], acc);
                acc = fmaf(zv.w, w1c[4*m+3], acc);
            }
            h1[l] = fast_tanh(acc);   // lanes 50..63 write 0 (b1c=0, w1c=0)
            __syncthreads();

            // ---- phase B: dz[2l],dz[2l+1] = tanh(b2 + sum_k h1[k]*W2[k][...]) ----
            float2 d2 = b2p;
            #pragma unroll
            for (int mb = 0; mb < MIDP/4; ++mb){
                const float4 hv = *reinterpret_cast<const float4*>(&h1[4*mb]);
                d2.x = fmaf(hv.x, w2p[4*mb+0].x, d2.x);
                d2.y = fmaf(hv.x, w2p[4*mb+0].y, d2.y);
                d2.x = fmaf(hv.y, w2p[4*mb+1].x, d2.x);
                d2.y = fmaf(hv.y, w2p[4*mb+1].y, d2.y);
                d2.x = fmaf(hv.z, w2p[4*mb+2].x, d2.x);
                d2.y = fmaf(hv.z, w2p[4*mb+2].y, d2.y);
                d2.x = fmaf(hv.w, w2p[4*mb+3].x, d2.x);
                d2.y = fmaf(hv.w, w2p[4*mb+3].y, d2.y);
            }
            z2.x += hstep * fast_tanh(d2.x);
            z2.y += hstep * fast_tanh(d2.y);
            *reinterpret_cast<float2*>(&zx[2*l]) = z2;
            __syncthreads();
        }

        // ---- heads: lane l computes outputs (2l, 2l+1) of both heads ----
        float2 ps = bls1p, pm = blm1p;
        #pragma unroll 8
        for (int k = 0; k < HID; k += 4){
            const float4 zv = *reinterpret_cast<const float4*>(&zx[k]);
            const float2 a0 = *reinterpret_cast<const float2*>(&Wls1[(k+0)*HID + 2*l]);
            const float2 a1 = *reinterpret_cast<const float2*>(&Wls1[(k+1)*HID + 2*l]);
            const float2 a2 = *reinterpret_cast<const float2*>(&Wls1[(k+2)*HID + 2*l]);
            const float2 a3 = *reinterpret_cast<const float2*>(&Wls1[(k+3)*HID + 2*l]);
            const float2 m0 = *reinterpret_cast<const float2*>(&Wlm1[(k+0)*HID + 2*l]);
            const float2 m1 = *reinterpret_cast<const float2*>(&Wlm1[(k+1)*HID + 2*l]);
            const float2 m2 = *reinterpret_cast<const float2*>(&Wlm1[(k+2)*HID + 2*l]);
            const float2 m3 = *reinterpret_cast<const float2*>(&Wlm1[(k+3)*HID + 2*l]);
            ps.x = fmaf(zv.x, a0.x, ps.x); ps.y = fmaf(zv.x, a0.y, ps.y);
            ps.x = fmaf(zv.y, a1.x, ps.x); ps.y = fmaf(zv.y, a1.y, ps.y);
            ps.x = fmaf(zv.z, a2.x, ps.x); ps.y = fmaf(zv.z, a2.y, ps.y);
            ps.x = fmaf(zv.w, a3.x, ps.x); ps.y = fmaf(zv.w, a3.y, ps.y);
            pm.x = fmaf(zv.x, m0.x, pm.x); pm.y = fmaf(zv.x, m0.y, pm.y);
            pm.x = fmaf(zv.y, m1.x, pm.x); pm.y = fmaf(zv.y, m1.y, pm.y);
            pm.x = fmaf(zv.z, m2.x, pm.x); pm.y = fmaf(zv.z, m2.y, pm.y);
            pm.x = fmaf(zv.w, m3.x, pm.x); pm.y = fmaf(zv.w, m3.y, pm.y);
        }
        ps.x = fast_tanh(ps.x); ps.y = fast_tanh(ps.y);
        pm.x = fast_tanh(pm.x); pm.y = fast_tanh(pm.y);

        float sred = ps.x*wls2p.x + ps.y*wls2p.y;
        float mred = pm.x*wls2p.x + pm.y*wls2p.y;
        #pragma unroll
        for (int off = 1; off < 64; off <<= 1){
            sred += __shfl_xor(sred, off, 64);
            mred += __shfl_xor(mred, off, 64);
        }
        if (l == 0){
            out[t]           = mred + bls2s;                 // mu (reuses ls2 — faithful)
            out[T_STEPS + t] = softplus_f(sred + bls2s);     // sigma
        }
    }
}

extern "C" void kernel_launch(void* const* d_in, const int* in_sizes, int n_in,
                              void* d_out, int out_size, void* d_ws, size_t ws_size,
                              hipStream_t stream)
{
    const float* x    = (const float*)d_in[0];
    const float* dt   = (const float*)d_in[1];
    const float* W1   = (const float*)d_in[2];
    const float* b1   = (const float*)d_in[3];
    const float* W2   = (const float*)d_in[4];
    const float* b2   = (const float*)d_in[5];
    const float* Wls1 = (const float*)d_in[6];
    const float* bls1 = (const float*)d_in[7];
    const float* wls2 = (const float*)d_in[8];
    const float* bls2 = (const float*)d_in[9];
    const float* Wlm1 = (const float*)d_in[10];
    const float* blm1 = (const float*)d_in[11];
    float* out = (float*)d_out;

    hipLaunchKernelGGL(lode_kernel, dim3(1), dim3(64), 0, stream,
                       x, dt, W1, b1, W2, b2, Wls1, bls1, wls2, bls2, Wlm1, blm1, out);
}

// Round 3
// 60109.344 us; speedup vs baseline: 1.7486x; 1.7486x over previous
//
#include <hip/hip_runtime.h>
#include <hip/hip_bf16.h>

#define T_STEPS 4096
#define HID 128
#define INP 8
#define MID 50
#define MIDP 52   // padded to multiple of 4
#define KSUB 10

__device__ __forceinline__ float fast_tanh(float x){
    float e = __expf(2.0f * x);
    return 1.0f - 2.0f / (e + 1.0f);
}
__device__ __forceinline__ float softplus_f(float x){
    return (x > 20.0f) ? x : __logf(1.0f + __expf(x));
}

// 2 waves, producer/consumer:
//   wave0: phase A (h1 = tanh(W1^T zx + b1)), sigma head.   W1 col per lane: 136 VGPR.
//   wave1: phase B (dz = tanh(W2^T h1 + b2)) + z state, mu head. W2 2 cols/lane: 104 VGPR.
// Exchange via LDS; exactly 2 barriers per substep in BOTH branches.
__global__ __launch_bounds__(128, 1)
void lode_kernel(const float* __restrict__ x, const float* __restrict__ dt,
                 const float* __restrict__ W1, const float* __restrict__ b1,
                 const float* __restrict__ W2, const float* __restrict__ b2,
                 const float* __restrict__ Wls1, const float* __restrict__ bls1,
                 const float* __restrict__ wls2, const float* __restrict__ bls2,
                 const float* __restrict__ Wlm1, const float* __restrict__ blm1,
                 float* __restrict__ out)
{
    __shared__ __align__(16) float zsh[HID];   // current z (broadcast buffer)
    __shared__ __align__(16) float h1sh[64];   // mid activations (50 real + pad)

    const int tid = threadIdx.x;
    const int wid = tid >> 6;
    const int l   = tid & 63;

    if (wid == 0){ zsh[2*l] = 0.0f; zsh[2*l+1] = 0.0f; }
    __syncthreads();

    if (wid == 0){
        // ================= wave 0: phase A + sigma head =================
        const int lc = (l < MID) ? l : 0;          // clamp: keep loads in-bounds
        float w1z[HID];                            // W1[k][l], k = 0..127 (z part)
        #pragma unroll
        for (int k = 0; k < HID; ++k){
            const float v = W1[k*MID + lc];
            w1z[k] = (l < MID) ? v : 0.0f;
        }
        float w1x[INP];                            // W1[128+j][l] (x part)
        #pragma unroll
        for (int j = 0; j < INP; ++j){
            const float v = W1[(HID+j)*MID + lc];
            w1x[j] = (l < MID) ? v : 0.0f;
        }
        const float  b1c   = (l < MID) ? b1[lc] : 0.0f;
        const float2 bls1p = make_float2(bls1[2*l], bls1[2*l+1]);
        const float2 wls2p = make_float2(wls2[2*l], wls2[2*l+1]);
        const float  bls2s = bls2[0];

        for (int t = 0; t < T_STEPS; ++t){
            // x_t is lane-uniform; fold x-part of the dot once per step
            const float4 xa = *reinterpret_cast<const float4*>(&x[t*INP]);
            const float4 xb = *reinterpret_cast<const float4*>(&x[t*INP+4]);
            float xacc = b1c;
            xacc = fmaf(xa.x, w1x[0], xacc); xacc = fmaf(xa.y, w1x[1], xacc);
            xacc = fmaf(xa.z, w1x[2], xacc); xacc = fmaf(xa.w, w1x[3], xacc);
            xacc = fmaf(xb.x, w1x[4], xacc); xacc = fmaf(xb.y, w1x[5], xacc);
            xacc = fmaf(xb.z, w1x[6], xacc); xacc = fmaf(xb.w, w1x[7], xacc);

            for (int s = 0; s < KSUB; ++s){
                // h1[l] = tanh(xacc + sum_k z[k] * W1[k][l]) — 4 indep chains
                float a0 = xacc, a1 = 0.0f, a2 = 0.0f, a3 = 0.0f;
                #pragma unroll
                for (int m = 0; m < HID/16; ++m){
                    const float4 z0 = *reinterpret_cast<const float4*>(&zsh[16*m+ 0]);
                    const float4 z1 = *reinterpret_cast<const float4*>(&zsh[16*m+ 4]);
                    const float4 z2 = *reinterpret_cast<const float4*>(&zsh[16*m+ 8]);
                    const float4 z3 = *reinterpret_cast<const float4*>(&zsh[16*m+12]);
                    a0 = fmaf(z0.x, w1z[16*m+ 0], a0); a0 = fmaf(z0.y, w1z[16*m+ 1], a0);
                    a0 = fmaf(z0.z, w1z[16*m+ 2], a0); a0 = fmaf(z0.w, w1z[16*m+ 3], a0);
                    a1 = fmaf(z1.x, w1z[16*m+ 4], a1); a1 = fmaf(z1.y, w1z[16*m+ 5], a1);
                    a1 = fmaf(z1.z, w1z[16*m+ 6], a1); a1 = fmaf(z1.w, w1z[16*m+ 7], a1);
                    a2 = fmaf(z2.x, w1z[16*m+ 8], a2); a2 = fmaf(z2.y, w1z[16*m+ 9], a2);
                    a2 = fmaf(z2.z, w1z[16*m+10], a2); a2 = fmaf(z2.w, w1z[16*m+11], a2);
                    a3 = fmaf(z3.x, w1z[16*m+12], a3); a3 = fmaf(z3.y, w1z[16*m+13], a3);
                    a3 = fmaf(z3.z, w1z[16*m+14], a3); a3 = fmaf(z3.w, w1z[16*m+15], a3);
                }
                h1sh[l] = fast_tanh((a0 + a1) + (a2 + a3));  // lanes >= 50 write tanh(0)=0
                __syncthreads();   // B1: h1 ready
                __syncthreads();   // B2: z updated by wave1
            }

            // ---- sigma head (reads final z of this step) ----
            float2 ps = bls1p;
            #pragma unroll
            for (int k = 0; k < HID; k += 4){
                const float4 zv = *reinterpret_cast<const float4*>(&zsh[k]);
                const float2 a0 = *reinterpret_cast<const float2*>(&Wls1[(k+0)*HID + 2*l]);
                const float2 a1 = *reinterpret_cast<const float2*>(&Wls1[(k+1)*HID + 2*l]);
                const float2 a2 = *reinterpret_cast<const float2*>(&Wls1[(k+2)*HID + 2*l]);
                const float2 a3 = *reinterpret_cast<const float2*>(&Wls1[(k+3)*HID + 2*l]);
                ps.x = fmaf(zv.x, a0.x, ps.x); ps.y = fmaf(zv.x, a0.y, ps.y);
                ps.x = fmaf(zv.y, a1.x, ps.x); ps.y = fmaf(zv.y, a1.y, ps.y);
                ps.x = fmaf(zv.z, a2.x, ps.x); ps.y = fmaf(zv.z, a2.y, ps.y);
                ps.x = fmaf(zv.w, a3.x, ps.x); ps.y = fmaf(zv.w, a3.y, ps.y);
            }
            ps.x = fast_tanh(ps.x); ps.y = fast_tanh(ps.y);
            float sred = ps.x*wls2p.x + ps.y*wls2p.y;
            #pragma unroll
            for (int off = 1; off < 64; off <<= 1) sred += __shfl_xor(sred, off, 64);
            if (l == 0) out[T_STEPS + t] = softplus_f(sred + bls2s);
        }
    } else {
        // ================= wave 1: phase B + z state + mu head =================
        float2 w2p[MIDP];                          // W2[k][2l], W2[k][2l+1]
        #pragma unroll
        for (int k = 0; k < MIDP; ++k){
            if (k < MID) w2p[k] = make_float2(W2[k*HID + 2*l], W2[k*HID + 2*l+1]);
            else         w2p[k] = make_float2(0.0f, 0.0f);
        }
        const float2 b2p   = make_float2(b2[2*l],   b2[2*l+1]);
        const float2 blm1p = make_float2(blm1[2*l], blm1[2*l+1]);
        const float2 wls2p = make_float2(wls2[2*l], wls2[2*l+1]);
        const float  bls2s = bls2[0];
        float2 z2 = make_float2(0.0f, 0.0f);

        for (int t = 0; t < T_STEPS; ++t){
            const float hstep = (dt[2*t+1] - dt[2*t]) * (1.0f / KSUB);

            for (int s = 0; s < KSUB; ++s){
                __syncthreads();   // B1: h1 ready
                float2 d2 = b2p;
                #pragma unroll
                for (int mb = 0; mb < MIDP/4; ++mb){
                    const float4 hv = *reinterpret_cast<const float4*>(&h1sh[4*mb]);
                    d2.x = fmaf(hv.x, w2p[4*mb+0].x, d2.x); d2.y = fmaf(hv.x, w2p[4*mb+0].y, d2.y);
                    d2.x = fmaf(hv.y, w2p[4*mb+1].x, d2.x); d2.y = fmaf(hv.y, w2p[4*mb+1].y, d2.y);
                    d2.x = fmaf(hv.z, w2p[4*mb+2].x, d2.x); d2.y = fmaf(hv.z, w2p[4*mb+2].y, d2.y);
                    d2.x = fmaf(hv.w, w2p[4*mb+3].x, d2.x); d2.y = fmaf(hv.w, w2p[4*mb+3].y, d2.y);
                }
                z2.x += hstep * fast_tanh(d2.x);
                z2.y += hstep * fast_tanh(d2.y);
                *reinterpret_cast<float2*>(&zsh[2*l]) = z2;
                __syncthreads();   // B2: z ready
            }

            // ---- mu head ----
            float2 pm = blm1p;
            #pragma unroll
            for (int k = 0; k < HID; k += 4){
                const float4 zv = *reinterpret_cast<const float4*>(&zsh[k]);
                const float2 m0 = *reinterpret_cast<const float2*>(&Wlm1[(k+0)*HID + 2*l]);
                const float2 m1 = *reinterpret_cast<const float2*>(&Wlm1[(k+1)*HID + 2*l]);
                const float2 m2 = *reinterpret_cast<const float2*>(&Wlm1[(k+2)*HID + 2*l]);
                const float2 m3 = *reinterpret_cast<const float2*>(&Wlm1[(k+3)*HID + 2*l]);
                pm.x = fmaf(zv.x, m0.x, pm.x); pm.y = fmaf(zv.x, m0.y, pm.y);
                pm.x = fmaf(zv.y, m1.x, pm.x); pm.y = fmaf(zv.y, m1.y, pm.y);
                pm.x = fmaf(zv.z, m2.x, pm.x); pm.y = fmaf(zv.z, m2.y, pm.y);
                pm.x = fmaf(zv.w, m3.x, pm.x); pm.y = fmaf(zv.w, m3.y, pm.y);
            }
            pm.x = fast_tanh(pm.x); pm.y = fast_tanh(pm.y);
            float mred = pm.x*wls2p.x + pm.y*wls2p.y;
            #pragma unroll
            for (int off = 1; off < 64; off <<= 1) mred += __shfl_xor(mred, off, 64);
            if (l == 0) out[t] = mred + bls2s;   // mu (reuses ls2 — faithful)
        }
    }
}

extern "C" void kernel_launch(void* const* d_in, const int* in_sizes, int n_in,
                              void* d_out, int out_size, void* d_ws, size_t ws_size,
                              hipStream_t stream)
{
    const float* x    = (const float*)d_in[0];
    const float* dt   = (const float*)d_in[1];
    const float* W1   = (const float*)d_in[2];
    const float* b1   = (const float*)d_in[3];
    const float* W2   = (const float*)d_in[4];
    const float* b2   = (const float*)d_in[5];
    const float* Wls1 = (const float*)d_in[6];
    const float* bls1 = (const float*)d_in[7];
    const float* wls2 = (const float*)d_in[8];
    const float* bls2 = (const float*)d_in[9];
    const float* Wlm1 = (const float*)d_in[10];
    const float* blm1 = (const float*)d_in[11];
    float* out = (float*)d_out;

    hipLaunchKernelGGL(lode_kernel, dim3(1), dim3(128), 0, stream,
                       x, dt, W1, b1, W2, b2, Wls1, bls1, wls2, bls2, Wlm1, blm1, out);
}

// Round 4
// 40728.693 us; speedup vs baseline: 2.5806x; 1.4758x over previous
//
#include <hip/hip_runtime.h>
#include <hip/hip_bf16.h>

#define T_STEPS 4096
#define HID 128
#define INP 8
#define MID 50
#define MIDP 52   // padded to multiple of 4
#define KSUB 10

typedef float v2f __attribute__((ext_vector_type(2)));

__device__ __forceinline__ v2f mk2(float a, float b){ v2f r; r.x = a; r.y = b; return r; }
__device__ __forceinline__ v2f bc2(float s){ v2f r; r.x = s; r.y = s; return r; }

__device__ __forceinline__ v2f fma2(v2f a, v2f b, v2f c){
#if __has_builtin(__builtin_elementwise_fma)
    return __builtin_elementwise_fma(a, b, c);
#else
    c.x = fmaf(a.x, b.x, c.x); c.y = fmaf(a.y, b.y, c.y); return c;
#endif
}

__device__ __forceinline__ float fast_tanh(float x){
    float e = __expf(2.0f * x);
    return 1.0f - 2.0f / (e + 1.0f);
}
__device__ __forceinline__ float softplus_f(float x){
    return (x > 20.0f) ? x : __logf(1.0f + __expf(x));
}

// Barrier WITHOUT the vmcnt(0) drain __syncthreads() implies.
// We only communicate through LDS: lgkmcnt(0) orders our ds_writes before
// s_barrier; outstanding global loads (x, dt, head weights) stay in flight.
__device__ __forceinline__ void wg_barrier(){
    asm volatile("s_waitcnt lgkmcnt(0)\n\ts_barrier" ::: "memory");
}

// 2 waves, producer/consumer, 2 barriers per substep:
//   wave0: phase A (h1 = tanh(W1^T [z;x] + b1)) + sigma head. W1 col per lane.
//   wave1: phase B (z += hstep*tanh(W2^T h1 + b2)) + mu head. W2 2 cols/lane.
__global__ __launch_bounds__(128, 1)
void lode_kernel(const float* __restrict__ x, const float* __restrict__ dt,
                 const float* __restrict__ W1, const float* __restrict__ b1,
                 const float* __restrict__ W2, const float* __restrict__ b2,
                 const float* __restrict__ Wls1, const float* __restrict__ bls1,
                 const float* __restrict__ wls2, const float* __restrict__ bls2,
                 const float* __restrict__ Wlm1, const float* __restrict__ blm1,
                 float* __restrict__ out)
{
    __shared__ __align__(16) float zsh[HID];   // current z (broadcast buffer)
    __shared__ __align__(16) float h1sh[64];   // mid activations (50 real + pad)

    const int tid = threadIdx.x;
    const int wid = tid >> 6;
    const int l   = tid & 63;

    if (wid == 0){ zsh[2*l] = 0.0f; zsh[2*l+1] = 0.0f; }
    __syncthreads();   // init barrier (full drain fine, once)

    if (wid == 0){
        // ================= wave 0: phase A + sigma head =================
        const int lc = (l < MID) ? l : 0;      // clamp loads in-bounds
        // W1 z-part as packed pairs: w1[i] = (W1[2i][l], W1[2i+1][l])
        v2f w1[HID/2];
        #pragma unroll
        for (int i = 0; i < HID/2; ++i){
            const float a = W1[(2*i  )*MID + lc];
            const float b = W1[(2*i+1)*MID + lc];
            w1[i] = (l < MID) ? mk2(a, b) : mk2(0.0f, 0.0f);
        }
        float w1x[INP];
        #pragma unroll
        for (int j = 0; j < INP; ++j){
            const float v = W1[(HID+j)*MID + lc];
            w1x[j] = (l < MID) ? v : 0.0f;
        }
        const float b1c   = (l < MID) ? b1[lc] : 0.0f;
        const v2f   bls1p = mk2(bls1[2*l], bls1[2*l+1]);
        const v2f   wls2p = mk2(wls2[2*l], wls2[2*l+1]);
        const float bls2s = bls2[0];

        for (int t = 0; t < T_STEPS; ++t){
            // x_t lane-uniform: fold x-part of the dot once per step
            const float4 xa = *reinterpret_cast<const float4*>(&x[t*INP]);
            const float4 xb = *reinterpret_cast<const float4*>(&x[t*INP+4]);
            float xacc = b1c;
            xacc = fmaf(xa.x, w1x[0], xacc); xacc = fmaf(xa.y, w1x[1], xacc);
            xacc = fmaf(xa.z, w1x[2], xacc); xacc = fmaf(xa.w, w1x[3], xacc);
            xacc = fmaf(xb.x, w1x[4], xacc); xacc = fmaf(xb.y, w1x[5], xacc);
            xacc = fmaf(xb.z, w1x[6], xacc); xacc = fmaf(xb.w, w1x[7], xacc);

            for (int s = 0; s < KSUB; ++s){
                // h1[l] = tanh(xacc + sum_k z[k]*W1[k][l]) — 4 packed chains
                v2f a0 = mk2(xacc, 0.0f), a1 = bc2(0.0f), a2 = bc2(0.0f), a3 = bc2(0.0f);
                #pragma unroll
                for (int m = 0; m < HID/16; ++m){
                    const float4 q0 = *reinterpret_cast<const float4*>(&zsh[16*m+ 0]);
                    const float4 q1 = *reinterpret_cast<const float4*>(&zsh[16*m+ 4]);
                    const float4 q2 = *reinterpret_cast<const float4*>(&zsh[16*m+ 8]);
                    const float4 q3 = *reinterpret_cast<const float4*>(&zsh[16*m+12]);
                    a0 = fma2(mk2(q0.x, q0.y), w1[8*m+0], a0);
                    a1 = fma2(mk2(q0.z, q0.w), w1[8*m+1], a1);
                    a2 = fma2(mk2(q1.x, q1.y), w1[8*m+2], a2);
                    a3 = fma2(mk2(q1.z, q1.w), w1[8*m+3], a3);
                    a0 = fma2(mk2(q2.x, q2.y), w1[8*m+4], a0);
                    a1 = fma2(mk2(q2.z, q2.w), w1[8*m+5], a1);
                    a2 = fma2(mk2(q3.x, q3.y), w1[8*m+6], a2);
                    a3 = fma2(mk2(q3.z, q3.w), w1[8*m+7], a3);
                }
                const v2f aa = (a0 + a1) + (a2 + a3);
                h1sh[l] = fast_tanh(aa.x + aa.y);   // lanes >= 50 write tanh(0)=0
                wg_barrier();   // B1: h1 ready
                wg_barrier();   // B2: z updated by wave1
            }

            // ---- sigma head (reads final z of this step) ----
            v2f ps = bls1p;
            #pragma unroll 4
            for (int k = 0; k < HID; k += 4){
                const float4 zv = *reinterpret_cast<const float4*>(&zsh[k]);
                const v2f a0 = *reinterpret_cast<const v2f*>(&Wls1[(k+0)*HID + 2*l]);
                const v2f a1 = *reinterpret_cast<const v2f*>(&Wls1[(k+1)*HID + 2*l]);
                const v2f a2 = *reinterpret_cast<const v2f*>(&Wls1[(k+2)*HID + 2*l]);
                const v2f a3 = *reinterpret_cast<const v2f*>(&Wls1[(k+3)*HID + 2*l]);
                ps = fma2(bc2(zv.x), a0, ps);
                ps = fma2(bc2(zv.y), a1, ps);
                ps = fma2(bc2(zv.z), a2, ps);
                ps = fma2(bc2(zv.w), a3, ps);
            }
            ps.x = fast_tanh(ps.x); ps.y = fast_tanh(ps.y);
            float sred = ps.x*wls2p.x + ps.y*wls2p.y;
            #pragma unroll
            for (int off = 1; off < 64; off <<= 1) sred += __shfl_xor(sred, off, 64);
            if (l == 0) out[T_STEPS + t] = softplus_f(sred + bls2s);
        }
    } else {
        // ================= wave 1: phase B + z state + mu head =================
        v2f w2p[MIDP];                         // (W2[k][2l], W2[k][2l+1])
        #pragma unroll
        for (int k = 0; k < MIDP; ++k){
            if (k < MID) w2p[k] = mk2(W2[k*HID + 2*l], W2[k*HID + 2*l+1]);
            else         w2p[k] = mk2(0.0f, 0.0f);
        }
        const v2f   b2p   = mk2(b2[2*l],   b2[2*l+1]);
        const v2f   blm1p = mk2(blm1[2*l], blm1[2*l+1]);
        const v2f   wls2p = mk2(wls2[2*l], wls2[2*l+1]);
        const float bls2s = bls2[0];
        v2f z2 = bc2(0.0f);

        for (int t = 0; t < T_STEPS; ++t){
            const float2 dtp = *reinterpret_cast<const float2*>(&dt[2*t]);
            const float hstep = (dtp.y - dtp.x) * (1.0f / KSUB);

            for (int s = 0; s < KSUB; ++s){
                wg_barrier();   // B1: h1 ready
                v2f d0 = b2p, d1 = bc2(0.0f), d2 = bc2(0.0f), d3 = bc2(0.0f);
                #pragma unroll
                for (int q = 0; q < MIDP/4; ++q){
                    const float4 hq = *reinterpret_cast<const float4*>(&h1sh[4*q]);
                    d0 = fma2(bc2(hq.x), w2p[4*q+0], d0);
                    d1 = fma2(bc2(hq.y), w2p[4*q+1], d1);
                    d2 = fma2(bc2(hq.z), w2p[4*q+2], d2);
                    d3 = fma2(bc2(hq.w), w2p[4*q+3], d3);
                }
                const v2f dd = (d0 + d1) + (d2 + d3);
                z2.x += hstep * fast_tanh(dd.x);
                z2.y += hstep * fast_tanh(dd.y);
                *reinterpret_cast<v2f*>(&zsh[2*l]) = z2;
                wg_barrier();   // B2: z ready
            }

            // ---- mu head ----
            v2f pm = blm1p;
            #pragma unroll 4
            for (int k = 0; k < HID; k += 4){
                const float4 zv = *reinterpret_cast<const float4*>(&zsh[k]);
                const v2f m0 = *reinterpret_cast<const v2f*>(&Wlm1[(k+0)*HID + 2*l]);
                const v2f m1 = *reinterpret_cast<const v2f*>(&Wlm1[(k+1)*HID + 2*l]);
                const v2f m2 = *reinterpret_cast<const v2f*>(&Wlm1[(k+2)*HID + 2*l]);
                const v2f m3 = *reinterpret_cast<const v2f*>(&Wlm1[(k+3)*HID + 2*l]);
                pm = fma2(bc2(zv.x), m0, pm);
                pm = fma2(bc2(zv.y), m1, pm);
                pm = fma2(bc2(zv.z), m2, pm);
                pm = fma2(bc2(zv.w), m3, pm);
            }
            pm.x = fast_tanh(pm.x); pm.y = fast_tanh(pm.y);
            float mred = pm.x*wls2p.x + pm.y*wls2p.y;
            #pragma unroll
            for (int off = 1; off < 64; off <<= 1) mred += __shfl_xor(mred, off, 64);
            if (l == 0) out[t] = mred + bls2s;   // mu (reuses ls2 — faithful)
        }
    }
}

extern "C" void kernel_launch(void* const* d_in, const int* in_sizes, int n_in,
                              void* d_out, int out_size, void* d_ws, size_t ws_size,
                              hipStream_t stream)
{
    const float* x    = (const float*)d_in[0];
    const float* dt   = (const float*)d_in[1];
    const float* W1   = (const float*)d_in[2];
    const float* b1   = (const float*)d_in[3];
    const float* W2   = (const float*)d_in[4];
    const float* b2   = (const float*)d_in[5];
    const float* Wls1 = (const float*)d_in[6];
    const float* bls1 = (const float*)d_in[7];
    const float* wls2 = (const float*)d_in[8];
    const float* bls2 = (const float*)d_in[9];
    const float* Wlm1 = (const float*)d_in[10];
    const float* blm1 = (const float*)d_in[11];
    float* out = (float*)d_out;

    hipLaunchKernelGGL(lode_kernel, dim3(1), dim3(128), 0, stream,
                       x, dt, W1, b1, W2, b2, Wls1, bls1, wls2, bls2, Wlm1, blm1, out);
}